// Round 2
// baseline (3102.750 us; speedup 1.0000x reference)
//
#include <hip/hip_runtime.h>
#include <math.h>

#define HWc 65536
#define Wd 256
#define Hd 256

// ---- ws layout (float offsets), small buffers FIRST ----
static const size_t SSQ_Q_OFF = 0;        // 768
static const size_t SSQ_K_OFF = 768;      // 768
static const size_t ATTN_OFF  = 1536;     // 8*4*576 = 18432
static const size_t W2T_OFF   = 19968;    // 8*96*96 = 73728
static const size_t KVW1T_OFF = 93696;    // 96*192 = 18432
static const size_t QW1T_OFF  = 112128;   // 96*96 = 9216
static const size_t WS1_OFF   = 121344;   // 8*96*HWc = 50331648 floats (201 MB)
// total = 50,452,992 floats = 201.8 MB

// ---- transpose [O][I] -> [I][O] ----
__global__ void transpose_w_kernel(const float* __restrict__ w, float* __restrict__ wT,
                                   int O, int I) {
    int idx = blockIdx.x * 256 + threadIdx.x;
    if (idx < O * I) {
        int o = idx / I, c = idx % I;
        wT[(size_t)c * O + o] = w[idx];
    }
}

// ---- 1x1 conv, Cin=96, Cout=96 (via woff into a [96][cstride] wT) ----
// out[b][m][px] = sum_c wT[c][woff+m] * in[b][c][px]
__global__ __launch_bounds__(256) void conv1x1_96(
    const float* __restrict__ in, const float* __restrict__ wT,
    int cstride, int woff, float* __restrict__ out)
{
    int b = blockIdx.y;
    int px = blockIdx.x * 256 + threadIdx.x;
    const float* inb = in + (size_t)b * 96 * HWc + px;
    float* outb = out + (size_t)b * 96 * HWc + px;
#pragma unroll 1
    for (int m0 = 0; m0 < 96; m0 += 48) {
        float acc[48];
#pragma unroll
        for (int m = 0; m < 48; ++m) acc[m] = 0.f;
        for (int c = 0; c < 96; ++c) {
            float v = inb[(size_t)c * HWc];
            const float* wc = wT + c * cstride + woff + m0;  // thread-uniform -> s_load
#pragma unroll
            for (int m = 0; m < 48; ++m) acc[m] = fmaf(wc[m], v, acc[m]);
        }
#pragma unroll
        for (int m = 0; m < 48; ++m) outb[(size_t)(m0 + m) * HWc] = acc[m];
    }
}

// ---- depthwise 3x3 (pad=1) + per-channel sumsq ----
__global__ __launch_bounds__(256) void depthwise3x3_kernel(
    const float* __restrict__ in, const float* __restrict__ wq,
    float* __restrict__ out, float* __restrict__ ssq_q)
{
    __shared__ float red[4];
    int y = blockIdx.x, c = blockIdx.y, b = blockIdx.z;
    int x = threadIdx.x;

    const float* inc = in + ((size_t)(b * 96 + c)) * HWc;
    float wv[9];
    const float* wp = wq + (size_t)c * 9;
#pragma unroll
    for (int t = 0; t < 9; ++t) wv[t] = wp[t];

    float acc = 0.f;
#pragma unroll
    for (int ky = 0; ky < 3; ++ky) {
        int yy = y + ky - 1;
        if ((unsigned)yy < (unsigned)Hd) {
            const float* r0 = inc + (size_t)yy * Wd;
#pragma unroll
            for (int kx = 0; kx < 3; ++kx) {
                int xx = x + kx - 1;
                if ((unsigned)xx < (unsigned)Wd)
                    acc += wv[ky * 3 + kx] * r0[xx];
            }
        }
    }
    out[((size_t)(b * 96 + c)) * HWc + (size_t)y * Wd + x] = acc;

    float p = acc * acc;
#pragma unroll
    for (int off = 32; off; off >>= 1) p += __shfl_down(p, off, 64);
    int lane = x & 63, wvi = x >> 6;
    if (lane == 0) red[wvi] = p;
    __syncthreads();
    if (x == 0) atomicAdd(&ssq_q[b * 96 + c], red[0] + red[1] + red[2] + red[3]);
}

// ---- fused: grouped3x3(kmid) -> k tile (LDS, never stored) + logits Gram + ssq_k ----
// grid (32 ytiles, 4 heads, 8 b), 256 thr. Per block: 8 rows x 2 px-halves of 128.
__global__ __launch_bounds__(256) void k_logits_kernel(
    const float* __restrict__ mid,   // kmid [b][96][HW]
    const float* __restrict__ w2,    // kvw2 [192][2][3][3]
    const float* __restrict__ qg,    // q [b][96][HW] (in d_out)
    float* __restrict__ attn_raw,    // [b][4][24][24]
    float* __restrict__ ssq_k)       // [b][96]
{
    __shared__ float qs[24][129];
    __shared__ float ks[24][129];
    __shared__ float wls[24][18];
    __shared__ float redbuf[4][576];

    int yt = blockIdx.x, h = blockIdx.y, b = blockIdx.z;
    int t = threadIdx.x, lane = t & 63, wvi = t >> 6;
    int i0 = (lane >> 3) * 3, j0 = (lane & 7) * 3;

    const float* midb = mid + ((size_t)b * 96 + h * 24) * HWc;
    const float* qb   = qg  + ((size_t)b * 96 + h * 24) * HWc;

    if (t < 432) wls[t / 18][t % 18] = w2[(size_t)(h * 24 + t / 18) * 18 + (t % 18)];

    float acc[3][3];
#pragma unroll
    for (int a = 0; a < 3; ++a)
#pragma unroll
        for (int c2 = 0; c2 < 3; ++c2) acc[a][c2] = 0.f;
    float ssq_acc = 0.f;

    for (int r = 0; r < 8; ++r) {
        int y = yt * 8 + r;
#pragma unroll 1
        for (int half = 0; half < 2; ++half) {
            int x0 = half * 128;
            __syncthreads();   // protect LDS from previous chunk's readers
            // stage q: 24 ch x 128 px
#pragma unroll
            for (int m = 0; m < 12; ++m) {
                int idx = m * 256 + t;
                int i = idx >> 7, px = idx & 127;
                qs[i][px] = qb[(size_t)i * HWc + (size_t)y * Wd + x0 + px];
            }
            // compute+stage k: 24 ch x 128 px (j wave-uniform -> wls broadcast)
#pragma unroll
            for (int m = 0; m < 12; ++m) {
                int idx = m * 256 + t;
                int j = idx >> 7, px = idx & 127;
                int xg = x0 + px;
                const float* m0 = midb + (size_t)(j & ~1) * HWc;
                const float* m1 = m0 + HWc;
                float kv = 0.f;
#pragma unroll
                for (int dy = 0; dy < 3; ++dy) {
                    int yy = y + dy - 1;
                    if ((unsigned)yy < (unsigned)Hd) {
                        const float* r0 = m0 + (size_t)yy * Wd;
                        const float* r1 = m1 + (size_t)yy * Wd;
#pragma unroll
                        for (int dx = 0; dx < 3; ++dx) {
                            int xx = xg + dx - 1;
                            if ((unsigned)xx < (unsigned)Wd)
                                kv += wls[j][dy * 3 + dx] * r0[xx]
                                    + wls[j][9 + dy * 3 + dx] * r1[xx];
                        }
                    }
                }
                ks[j][px] = kv;
            }
            __syncthreads();
            // ssq_k partials (threads 0..191: j = t>>3, 8 lanes stride the 128 px)
            if (t < 192) {
                int j = t >> 3, s = t & 7;
                float sum = 0.f;
#pragma unroll
                for (int u = 0; u < 16; ++u) { float v = ks[j][s + 8 * u]; sum += v * v; }
                ssq_acc += sum;
            }
            // Gram: each lane 3x3 (i,j) tile over its wave's 32-px strip
            int n0 = wvi * 32;
#pragma unroll 4
            for (int nn = 0; nn < 32; ++nn) {
                int n = n0 + nn;
                float q0 = qs[i0][n], q1 = qs[i0 + 1][n], q2 = qs[i0 + 2][n];
                float k0 = ks[j0][n], k1 = ks[j0 + 1][n], k2 = ks[j0 + 2][n];
                acc[0][0] += q0 * k0; acc[0][1] += q0 * k1; acc[0][2] += q0 * k2;
                acc[1][0] += q1 * k0; acc[1][1] += q1 * k1; acc[1][2] += q1 * k2;
                acc[2][0] += q2 * k0; acc[2][1] += q2 * k1; acc[2][2] += q2 * k2;
            }
        }
    }

    // ssq_k flush
    if (t < 192) {
        float v = ssq_acc;
        v += __shfl_down(v, 4, 8);
        v += __shfl_down(v, 2, 8);
        v += __shfl_down(v, 1, 8);
        if ((t & 7) == 0) atomicAdd(&ssq_k[b * 96 + h * 24 + (t >> 3)], v);
    }
    // cross-wave reduce of the Gram tile, then split-px atomics (32 blocks per (b,h))
    __syncthreads();
#pragma unroll
    for (int a = 0; a < 3; ++a)
#pragma unroll
        for (int c2 = 0; c2 < 3; ++c2)
            redbuf[wvi][(i0 + a) * 24 + (j0 + c2)] = acc[a][c2];
    __syncthreads();
    for (int p = t; p < 576; p += 256) {
        float s4 = redbuf[0][p] + redbuf[1][p] + redbuf[2][p] + redbuf[3][p];
        atomicAdd(&attn_raw[((size_t)b * 4 + h) * 576 + p], s4);
    }
}

// ---- softmax (+temperature, +1/(|q||k|)) then fold proj_w -> W2T[b][dv][co] ----
__global__ __launch_bounds__(256) void softmax_fold_kernel(
    const float* __restrict__ attn_raw,
    const float* __restrict__ ssq_q, const float* __restrict__ ssq_k,
    const float* __restrict__ temp, const float* __restrict__ projw,
    float* __restrict__ W2T)
{
    __shared__ float s[24][25];
    __shared__ float rq[24], rk[24];
    int h = blockIdx.x, b = blockIdx.y;
    int t = threadIdx.x;

    if (t < 24) {
        rq[t] = 1.f / fmaxf(sqrtf(ssq_q[b * 96 + h * 24 + t]), 1e-12f);
        rk[t] = 1.f / fmaxf(sqrtf(ssq_k[b * 96 + h * 24 + t]), 1e-12f);
    }
    __syncthreads();
    float T = temp[h];
    for (int p = t; p < 576; p += 256) {
        int i = p / 24, j = p % 24;
        s[i][j] = attn_raw[(size_t)(b * 4 + h) * 576 + p] * T * rq[i] * rk[j];
    }
    __syncthreads();
    if (t < 24) {
        float m = -1e30f;
#pragma unroll
        for (int j = 0; j < 24; ++j) m = fmaxf(m, s[t][j]);
        float sum = 0.f;
#pragma unroll
        for (int j = 0; j < 24; ++j) { float e = __expf(s[t][j] - m); s[t][j] = e; sum += e; }
        float inv = 1.f / sum;
#pragma unroll
        for (int j = 0; j < 24; ++j) s[t][j] *= inv;
    }
    __syncthreads();
    // W2T[b][h*24+d][co] = sum_c projw[co*96 + h*24 + c] * s[c][d]
    for (int m_ = t; m_ < 96 * 24; m_ += 256) {
        int d = m_ % 24, co = m_ / 24;
        float acc = 0.f;
#pragma unroll
        for (int c = 0; c < 24; ++c)
            acc += projw[co * 96 + h * 24 + c] * s[c][d];
        W2T[(size_t)b * 9216 + (size_t)(h * 24 + d) * 96 + co] = acc;
    }
}

// ---- fused: grouped3x3(vmid) -> v (regs, never stored) + out = W2 . v ----
// grid (256 y, 8 b), 256 thr; thread = one pixel, 96 output-channel accumulators.
__global__ __launch_bounds__(256) void v_proj_kernel(
    const float* __restrict__ mid,   // vmid [b][96][HW]
    const float* __restrict__ w2,    // kvw2
    const float* __restrict__ W2T,   // [b][96(dv)][96(co)]
    float* __restrict__ out)
{
    int y = blockIdx.x, b = blockIdx.y;
    int x = threadIdx.x;
    const float* midb = mid + (size_t)b * 96 * HWc;
    const float* wfold = W2T + (size_t)b * 9216;

    float acc[96];
#pragma unroll
    for (int m = 0; m < 96; ++m) acc[m] = 0.f;

#pragma unroll 1
    for (int g = 0; g < 48; ++g) {
        const float* m0 = midb + (size_t)(2 * g) * HWc;
        const float* m1 = m0 + HWc;
        const float* wg = w2 + (size_t)(96 + 2 * g) * 18;  // uniform -> s_load
        float v0 = 0.f, v1 = 0.f;
#pragma unroll
        for (int dy = 0; dy < 3; ++dy) {
            int yy = y + dy - 1;
            if ((unsigned)yy < (unsigned)Hd) {
                const float* r0 = m0 + (size_t)yy * Wd;
                const float* r1 = m1 + (size_t)yy * Wd;
#pragma unroll
                for (int dx = 0; dx < 3; ++dx) {
                    int xx = x + dx - 1;
                    if ((unsigned)xx < (unsigned)Wd) {
                        float a0 = r0[xx], a1 = r1[xx];
                        v0 += wg[dy * 3 + dx] * a0 + wg[9  + dy * 3 + dx] * a1;
                        v1 += wg[18 + dy * 3 + dx] * a0 + wg[27 + dy * 3 + dx] * a1;
                    }
                }
            }
        }
        const float* f0 = wfold + (size_t)(2 * g) * 96;  // uniform -> s_load
        const float* f1 = f0 + 96;
#pragma unroll
        for (int m = 0; m < 96; ++m)
            acc[m] += f0[m] * v0 + f1[m] * v1;
    }
    float* outb = out + (size_t)b * 96 * HWc + (size_t)y * Wd + x;
#pragma unroll
    for (int m = 0; m < 96; ++m) outb[(size_t)m * HWc] = acc[m];
}

extern "C" void kernel_launch(void* const* d_in, const int* in_sizes, int n_in,
                              void* d_out, int out_size, void* d_ws, size_t ws_size,
                              hipStream_t stream) {
    const float* x     = (const float*)d_in[0];
    const float* z     = (const float*)d_in[1];
    const float* kvw1  = (const float*)d_in[2];
    const float* kvw2  = (const float*)d_in[3];
    const float* qw1   = (const float*)d_in[4];
    const float* qw2   = (const float*)d_in[5];
    const float* projw = (const float*)d_in[6];
    const float* temp  = (const float*)d_in[7];
    float* out = (float*)d_out;
    float* ws  = (float*)d_ws;
    (void)in_sizes; (void)n_in; (void)out_size; (void)ws_size;

    float* ssq_q = ws + SSQ_Q_OFF;
    float* ssq_k = ws + SSQ_K_OFF;
    float* attn  = ws + ATTN_OFF;
    float* W2T   = ws + W2T_OFF;
    float* kvw1T = ws + KVW1T_OFF;
    float* qw1T  = ws + QW1T_OFF;
    float* ws1   = ws + WS1_OFF;   // 201 MB ping-pong mid buffer

    // zero atomic accumulators (ssq_q, ssq_k, attn) — runs on every replay
    hipMemsetAsync(ws, 0, (768 + 768 + 18432) * sizeof(float), stream);

    transpose_w_kernel<<<dim3(72), 256, 0, stream>>>(kvw1, kvw1T, 192, 96);
    transpose_w_kernel<<<dim3(36), 256, 0, stream>>>(qw1, qw1T, 96, 96);

    // ---- q path ----
    conv1x1_96<<<dim3(256, 8), 256, 0, stream>>>(x, qw1T, 96, 0, ws1);          // q1
    depthwise3x3_kernel<<<dim3(256, 96, 8), 256, 0, stream>>>(ws1, qw2, out, ssq_q); // q -> d_out

    // ---- k path (kmid -> fused k+logits; k never materialized) ----
    conv1x1_96<<<dim3(256, 8), 256, 0, stream>>>(z, kvw1T, 192, 0, ws1);        // kmid
    k_logits_kernel<<<dim3(32, 4, 8), 256, 0, stream>>>(ws1, kvw2, out, attn, ssq_k);

    softmax_fold_kernel<<<dim3(4, 8), 256, 0, stream>>>(attn, ssq_q, ssq_k, temp, projw, W2T);

    // ---- v path (vmid -> fused v+proj; v never materialized) ----
    conv1x1_96<<<dim3(256, 8), 256, 0, stream>>>(z, kvw1T, 192, 96, ws1);       // vmid
    v_proj_kernel<<<dim3(256, 8), 256, 0, stream>>>(ws1, kvw2, W2T, out);
}

// Round 3
// 2002.117 us; speedup vs baseline: 1.5497x; 1.5497x over previous
//
#include <hip/hip_runtime.h>
#include <math.h>

#define HWc 65536
#define Wd 256
#define Hd 256

// ---- ws layout (float offsets), small buffers FIRST ----
static const size_t SSQ_Q_OFF = 0;        // 768
static const size_t SSQ_K_OFF = 768;      // 768
static const size_t ATTN_OFF  = 1536;     // 8*4*576 = 18432
static const size_t W2T_OFF   = 19968;    // 8*96*96 = 73728
static const size_t KVW1T_OFF = 93696;    // 96*192 = 18432
static const size_t QW1T_OFF  = 112128;   // 96*96 = 9216
static const size_t WS1_OFF   = 121344;   // 8*96*HWc = 50331648 floats (201 MB)

// ---- transpose [O][I] -> [I][O] ----
__global__ void transpose_w_kernel(const float* __restrict__ w, float* __restrict__ wT,
                                   int O, int I) {
    int idx = blockIdx.x * 256 + threadIdx.x;
    if (idx < O * I) {
        int o = idx / I, c = idx % I;
        wT[(size_t)c * O + o] = w[idx];
    }
}

// ---- 1x1 conv via LDS staging: block = 128 px, stage in[96][128] once ----
// out[b][woff+m][px] = sum_c wT[c][woff+m] * in[b][c][px]
__global__ __launch_bounds__(256) void conv1x1_lds(
    const float* __restrict__ in, const float* __restrict__ wT,
    int cstride, int woff, float* __restrict__ out)
{
    __shared__ float in_lds[96][128];
    int b = blockIdx.y;
    int px0 = blockIdx.x * 128;
    int t = threadIdx.x;
    const float* inb = in + (size_t)b * 96 * HWc + px0;

    // stage: 96*128 floats = 3072 f4 / 256 thr = 12 f4 each (coalesced)
#pragma unroll
    for (int m = 0; m < 12; ++m) {
        int fi = m * 256 + t;
        int c = fi >> 5;             // 32 f4 per channel row
        int xo = (fi & 31) * 4;
        *(float4*)&in_lds[c][xo] = *(const float4*)(inb + (size_t)c * HWc + xo);
    }
    __syncthreads();

    int x = t & 127;
    int mh = __builtin_amdgcn_readfirstlane(t >> 7);   // wave-uniform -> s_load weights
    float acc[48];
#pragma unroll
    for (int m = 0; m < 48; ++m) acc[m] = 0.f;
    const float* wbase = wT + woff + mh * 48;
#pragma unroll 4
    for (int c = 0; c < 96; ++c) {
        float v = in_lds[c][x];
        const float* wc = wbase + c * cstride;
#pragma unroll
        for (int m = 0; m < 48; ++m) acc[m] = fmaf(wc[m], v, acc[m]);
    }
    float* outb = out + (size_t)b * 96 * HWc + (size_t)(mh * 48) * HWc + px0 + x;
#pragma unroll
    for (int m = 0; m < 48; ++m) outb[(size_t)m * HWc] = acc[m];
}

// ---- depthwise 3x3 (pad=1) + per-channel sumsq ----
__global__ __launch_bounds__(256) void depthwise3x3_kernel(
    const float* __restrict__ in, const float* __restrict__ wq,
    float* __restrict__ out, float* __restrict__ ssq_q)
{
    __shared__ float red[4];
    int y = blockIdx.x, c = blockIdx.y, b = blockIdx.z;
    int x = threadIdx.x;

    const float* inc = in + ((size_t)(b * 96 + c)) * HWc;
    float wv[9];
    const float* wp = wq + (size_t)c * 9;
#pragma unroll
    for (int t = 0; t < 9; ++t) wv[t] = wp[t];

    float acc = 0.f;
#pragma unroll
    for (int ky = 0; ky < 3; ++ky) {
        int yy = y + ky - 1;
        if ((unsigned)yy < (unsigned)Hd) {
            const float* r0 = inc + (size_t)yy * Wd;
#pragma unroll
            for (int kx = 0; kx < 3; ++kx) {
                int xx = x + kx - 1;
                if ((unsigned)xx < (unsigned)Wd)
                    acc += wv[ky * 3 + kx] * r0[xx];
            }
        }
    }
    out[((size_t)(b * 96 + c)) * HWc + (size_t)y * Wd + x] = acc;

    float p = acc * acc;
#pragma unroll
    for (int off = 32; off; off >>= 1) p += __shfl_down(p, off, 64);
    int lane = x & 63, wvi = x >> 6;
    if (lane == 0) red[wvi] = p;
    __syncthreads();
    if (x == 0) atomicAdd(&ssq_q[b * 96 + c], red[0] + red[1] + red[2] + red[3]);
}

// ---- fused: grouped3x3(kmid) -> k row-tiles (LDS) + logits Gram + ssq_k ----
// grid (32 ybands, 4 heads, 8 b), 256 thr.
// Per row: threads 0..191 compute k (one pair per 16-thread group, weights in
// persistent regs, vectorized loads); threads 192..255 stage q. Then all 256
// threads do the 24x24 Gram via 3x3 lane tiles over f4 LDS reads.
__global__ __launch_bounds__(256) void k_logits_kernel(
    const float* __restrict__ mid,   // kmid [b][96][HW]
    const float* __restrict__ w2,    // kvw2 [192][2][3][3]
    const float* __restrict__ qg,    // q [b][96][HW] (in d_out)
    float* __restrict__ attn_raw,    // [b][4][24][24]
    float* __restrict__ ssq_k)       // [b][96]
{
    __shared__ float qs[24][260];
    __shared__ float ks[24][260];

    int yt = blockIdx.x, h = blockIdx.y, b = blockIdx.z;
    int t = threadIdx.x, lane = t & 63, wvi = t >> 6;
    int i0 = (lane >> 3) * 3, j0 = (lane & 7) * 3;

    const float* midb = mid + ((size_t)b * 96 + h * 24) * HWc;
    const float* qb   = qg  + ((size_t)b * 96 + h * 24) * HWc;

    // per-thread pair assignment (t<192): p = t>>4, 16 threads per pair
    int p = t >> 4;
    float wv[36];
    if (t < 192) {
        const float* wp = w2 + (size_t)(h * 24 + 2 * p) * 18;
#pragma unroll
        for (int i = 0; i < 36; ++i) wv[i] = wp[i];
    }

    float acc[3][3];
#pragma unroll
    for (int a = 0; a < 3; ++a)
#pragma unroll
        for (int c2 = 0; c2 < 3; ++c2) acc[a][c2] = 0.f;
    float ssq0 = 0.f, ssq1 = 0.f;

    for (int r = 0; r < 8; ++r) {
        int y = yt * 8 + r;
        __syncthreads();   // protect qs/ks from previous row's Gram readers

        if (t >= 192) {
            // stage q: 24 ch x 256 px = 1536 f4 / 64 thr = 24 f4 each
            int u = t & 63;
            const float* qrow = qb + (size_t)y * Wd;
#pragma unroll
            for (int m = 0; m < 24; ++m) {
                int xo = u * 4;
                *(float4*)&qs[m][xo] = *(const float4*)(qrow + (size_t)m * HWc + xo);
            }
        } else {
            // compute k for pair p: channels j=2p,2p+1 from mid channels 2p,2p+1
            const float* m0 = midb + (size_t)(2 * p) * HWc;
            const float* m1 = m0 + HWc;
#pragma unroll
            for (int s = 0; s < 4; ++s) {
                int x0 = (t & 15) * 4 + s * 64;
                float k0[4] = {0.f, 0.f, 0.f, 0.f};
                float k1[4] = {0.f, 0.f, 0.f, 0.f};
#pragma unroll
                for (int dy = 0; dy < 3; ++dy) {
                    int yy = y + dy - 1;
                    if ((unsigned)yy < (unsigned)Hd) {   // block-uniform branch
#pragma unroll
                        for (int ic = 0; ic < 2; ++ic) {
                            const float* base = (ic ? m1 : m0) + (size_t)yy * Wd;
                            float4 cv = *(const float4*)(base + x0);
                            float rr[6];
                            rr[0] = (x0 > 0) ? base[x0 - 1] : 0.f;
                            rr[1] = cv.x; rr[2] = cv.y; rr[3] = cv.z; rr[4] = cv.w;
                            rr[5] = (x0 < 252) ? base[x0 + 4] : 0.f;
                            int wb_ = ic * 9 + dy * 3;
#pragma unroll
                            for (int px = 0; px < 4; ++px) {
#pragma unroll
                                for (int dx = 0; dx < 3; ++dx) {
                                    k0[px] = fmaf(wv[wb_ + dx],      rr[px + dx], k0[px]);
                                    k1[px] = fmaf(wv[18 + wb_ + dx], rr[px + dx], k1[px]);
                                }
                            }
                        }
                    }
                }
#pragma unroll
                for (int px = 0; px < 4; ++px) {
                    ssq0 = fmaf(k0[px], k0[px], ssq0);
                    ssq1 = fmaf(k1[px], k1[px], ssq1);
                }
                *(float4*)&ks[2 * p][x0]     = *(float4*)k0;
                *(float4*)&ks[2 * p + 1][x0] = *(float4*)k1;
            }
        }
        __syncthreads();

        // Gram: wave strip of 64 px, f4 vectorized
        int n0 = wvi * 64;
#pragma unroll 4
        for (int nn = 0; nn < 16; ++nn) {
            int n = n0 + nn * 4;
            float4 q0v = *(const float4*)&qs[i0][n];
            float4 q1v = *(const float4*)&qs[i0 + 1][n];
            float4 q2v = *(const float4*)&qs[i0 + 2][n];
            float4 k0v = *(const float4*)&ks[j0][n];
            float4 k1v = *(const float4*)&ks[j0 + 1][n];
            float4 k2v = *(const float4*)&ks[j0 + 2][n];
            acc[0][0] += q0v.x*k0v.x + q0v.y*k0v.y + q0v.z*k0v.z + q0v.w*k0v.w;
            acc[0][1] += q0v.x*k1v.x + q0v.y*k1v.y + q0v.z*k1v.z + q0v.w*k1v.w;
            acc[0][2] += q0v.x*k2v.x + q0v.y*k2v.y + q0v.z*k2v.z + q0v.w*k2v.w;
            acc[1][0] += q1v.x*k0v.x + q1v.y*k0v.y + q1v.z*k0v.z + q1v.w*k0v.w;
            acc[1][1] += q1v.x*k1v.x + q1v.y*k1v.y + q1v.z*k1v.z + q1v.w*k1v.w;
            acc[1][2] += q1v.x*k2v.x + q1v.y*k2v.y + q1v.z*k2v.z + q1v.w*k2v.w;
            acc[2][0] += q2v.x*k0v.x + q2v.y*k0v.y + q2v.z*k0v.z + q2v.w*k0v.w;
            acc[2][1] += q2v.x*k1v.x + q2v.y*k1v.y + q2v.z*k1v.z + q2v.w*k1v.w;
            acc[2][2] += q2v.x*k2v.x + q2v.y*k2v.y + q2v.z*k2v.z + q2v.w*k2v.w;
        }
    }

    // ssq_k: reduce within each 16-thread pair-group, 2 atomics per group
    if (t < 192) {
        float s0 = ssq0, s1 = ssq1;
#pragma unroll
        for (int off = 8; off; off >>= 1) {
            s0 += __shfl_down(s0, off, 64);
            s1 += __shfl_down(s1, off, 64);
        }
        if ((t & 15) == 0) {
            atomicAdd(&ssq_k[b * 96 + h * 24 + 2 * p],     s0);
            atomicAdd(&ssq_k[b * 96 + h * 24 + 2 * p + 1], s1);
        }
    }

    // cross-wave reduce of Gram tiles (redbuf aliases qs), then atomics
    __syncthreads();
    float* redbuf = &qs[0][0];   // 4*576 floats fit in qs
#pragma unroll
    for (int a = 0; a < 3; ++a)
#pragma unroll
        for (int c2 = 0; c2 < 3; ++c2)
            redbuf[wvi * 576 + (i0 + a) * 24 + (j0 + c2)] = acc[a][c2];
    __syncthreads();
    for (int p_ = t; p_ < 576; p_ += 256) {
        float s4 = redbuf[p_] + redbuf[576 + p_] + redbuf[1152 + p_] + redbuf[1728 + p_];
        atomicAdd(&attn_raw[((size_t)b * 4 + h) * 576 + p_], s4);
    }
}

// ---- softmax (+temperature, +1/(|q||k|)) then fold proj_w -> W2T[b][dv][co] ----
__global__ __launch_bounds__(256) void softmax_fold_kernel(
    const float* __restrict__ attn_raw,
    const float* __restrict__ ssq_q, const float* __restrict__ ssq_k,
    const float* __restrict__ temp, const float* __restrict__ projw,
    float* __restrict__ W2T)
{
    __shared__ float s[24][25];
    __shared__ float rq[24], rk[24];
    int h = blockIdx.x, b = blockIdx.y;
    int t = threadIdx.x;

    if (t < 24) {
        rq[t] = 1.f / fmaxf(sqrtf(ssq_q[b * 96 + h * 24 + t]), 1e-12f);
        rk[t] = 1.f / fmaxf(sqrtf(ssq_k[b * 96 + h * 24 + t]), 1e-12f);
    }
    __syncthreads();
    float T = temp[h];
    for (int p = t; p < 576; p += 256) {
        int i = p / 24, j = p % 24;
        s[i][j] = attn_raw[(size_t)(b * 4 + h) * 576 + p] * T * rq[i] * rk[j];
    }
    __syncthreads();
    if (t < 24) {
        float m = -1e30f;
#pragma unroll
        for (int j = 0; j < 24; ++j) m = fmaxf(m, s[t][j]);
        float sum = 0.f;
#pragma unroll
        for (int j = 0; j < 24; ++j) { float e = __expf(s[t][j] - m); s[t][j] = e; sum += e; }
        float inv = 1.f / sum;
#pragma unroll
        for (int j = 0; j < 24; ++j) s[t][j] *= inv;
    }
    __syncthreads();
    for (int m_ = t; m_ < 96 * 24; m_ += 256) {
        int d = m_ % 24, co = m_ / 24;
        float acc = 0.f;
#pragma unroll
        for (int c = 0; c < 24; ++c)
            acc += projw[co * 96 + h * 24 + c] * s[c][d];
        W2T[(size_t)b * 9216 + (size_t)(h * 24 + d) * 96 + co] = acc;
    }
}

// ---- fused: grouped3x3(vmid) -> v (regs) + out = W2 . v ----
__global__ __launch_bounds__(256) void v_proj_kernel(
    const float* __restrict__ mid, const float* __restrict__ w2,
    const float* __restrict__ W2T, float* __restrict__ out)
{
    int y = blockIdx.x, b = blockIdx.y;
    int x = threadIdx.x;
    const float* midb = mid + (size_t)b * 96 * HWc;
    const float* wfold = W2T + (size_t)b * 9216;

    float acc[96];
#pragma unroll
    for (int m = 0; m < 96; ++m) acc[m] = 0.f;

#pragma unroll 1
    for (int g = 0; g < 48; ++g) {
        const float* m0 = midb + (size_t)(2 * g) * HWc;
        const float* m1 = m0 + HWc;
        const float* wg = w2 + (size_t)(96 + 2 * g) * 18;
        float v0 = 0.f, v1 = 0.f;
#pragma unroll
        for (int dy = 0; dy < 3; ++dy) {
            int yy = y + dy - 1;
            if ((unsigned)yy < (unsigned)Hd) {
                const float* r0 = m0 + (size_t)yy * Wd;
                const float* r1 = m1 + (size_t)yy * Wd;
#pragma unroll
                for (int dx = 0; dx < 3; ++dx) {
                    int xx = x + dx - 1;
                    if ((unsigned)xx < (unsigned)Wd) {
                        float a0 = r0[xx], a1 = r1[xx];
                        v0 += wg[dy * 3 + dx] * a0 + wg[9  + dy * 3 + dx] * a1;
                        v1 += wg[18 + dy * 3 + dx] * a0 + wg[27 + dy * 3 + dx] * a1;
                    }
                }
            }
        }
        const float* f0 = wfold + (size_t)(2 * g) * 96;
        const float* f1 = f0 + 96;
#pragma unroll
        for (int m = 0; m < 96; ++m)
            acc[m] += f0[m] * v0 + f1[m] * v1;
    }
    float* outb = out + (size_t)b * 96 * HWc + (size_t)y * Wd + x;
#pragma unroll
    for (int m = 0; m < 96; ++m) outb[(size_t)m * HWc] = acc[m];
}

extern "C" void kernel_launch(void* const* d_in, const int* in_sizes, int n_in,
                              void* d_out, int out_size, void* d_ws, size_t ws_size,
                              hipStream_t stream) {
    const float* x     = (const float*)d_in[0];
    const float* z     = (const float*)d_in[1];
    const float* kvw1  = (const float*)d_in[2];
    const float* kvw2  = (const float*)d_in[3];
    const float* qw1   = (const float*)d_in[4];
    const float* qw2   = (const float*)d_in[5];
    const float* projw = (const float*)d_in[6];
    const float* temp  = (const float*)d_in[7];
    float* out = (float*)d_out;
    float* ws  = (float*)d_ws;
    (void)in_sizes; (void)n_in; (void)out_size; (void)ws_size;

    float* ssq_q = ws + SSQ_Q_OFF;
    float* ssq_k = ws + SSQ_K_OFF;
    float* attn  = ws + ATTN_OFF;
    float* W2T   = ws + W2T_OFF;
    float* kvw1T = ws + KVW1T_OFF;
    float* qw1T  = ws + QW1T_OFF;
    float* ws1   = ws + WS1_OFF;

    hipMemsetAsync(ws, 0, (768 + 768 + 18432) * sizeof(float), stream);

    transpose_w_kernel<<<dim3(72), 256, 0, stream>>>(kvw1, kvw1T, 192, 96);
    transpose_w_kernel<<<dim3(36), 256, 0, stream>>>(qw1, qw1T, 96, 96);

    // ---- q path ----
    conv1x1_lds<<<dim3(512, 8), 256, 0, stream>>>(x, qw1T, 96, 0, ws1);              // q1
    depthwise3x3_kernel<<<dim3(256, 96, 8), 256, 0, stream>>>(ws1, qw2, out, ssq_q); // q

    // ---- k path ----
    conv1x1_lds<<<dim3(512, 8), 256, 0, stream>>>(z, kvw1T, 192, 0, ws1);            // kmid
    k_logits_kernel<<<dim3(32, 4, 8), 256, 0, stream>>>(ws1, kvw2, out, attn, ssq_k);

    softmax_fold_kernel<<<dim3(4, 8), 256, 0, stream>>>(attn, ssq_q, ssq_k, temp, projw, W2T);

    // ---- v path ----
    conv1x1_lds<<<dim3(512, 8), 256, 0, stream>>>(z, kvw1T, 192, 96, ws1);           // vmid
    v_proj_kernel<<<dim3(256, 8), 256, 0, stream>>>(ws1, kvw2, W2T, out);
}

// Round 4
// 1380.889 us; speedup vs baseline: 2.2469x; 1.4499x over previous
//
#include <hip/hip_runtime.h>
#include <math.h>

#define HWc 65536
#define Wd 256
#define Hd 256

// ---- ws layout (float offsets), small buffers FIRST ----
static const size_t SSQ_Q_OFF = 0;        // 768
static const size_t SSQ_K_OFF = 768;      // 768
static const size_t ATTN_OFF  = 1536;     // 8*4*576 = 18432
static const size_t W2T_OFF   = 19968;    // 8*96*96 = 73728
static const size_t KVW1T_OFF = 93696;    // 96*192 = 18432
static const size_t QW1T_OFF  = 112128;   // 96*96 = 9216
static const size_t WS1_OFF   = 121344;   // 8*96*HWc = 50331648 floats (201 MB)

// ---- transpose [O][I] -> [I][O] ----
__global__ void transpose_w_kernel(const float* __restrict__ w, float* __restrict__ wT,
                                   int O, int I) {
    int idx = blockIdx.x * 256 + threadIdx.x;
    if (idx < O * I) {
        int o = idx / I, c = idx % I;
        wT[(size_t)c * O + o] = w[idx];
    }
}

// ---- 1x1 conv via LDS staging: block = 128 px, stage in[96][128] once ----
__global__ __launch_bounds__(256) void conv1x1_lds(
    const float* __restrict__ in, const float* __restrict__ wT,
    int cstride, int woff, float* __restrict__ out)
{
    __shared__ float in_lds[96][128];
    int b = blockIdx.y;
    int px0 = blockIdx.x * 128;
    int t = threadIdx.x;
    const float* inb = in + (size_t)b * 96 * HWc + px0;

#pragma unroll
    for (int m = 0; m < 12; ++m) {
        int fi = m * 256 + t;
        int c = fi >> 5;
        int xo = (fi & 31) * 4;
        *(float4*)&in_lds[c][xo] = *(const float4*)(inb + (size_t)c * HWc + xo);
    }
    __syncthreads();

    int x = t & 127;
    int mh = __builtin_amdgcn_readfirstlane(t >> 7);
    float acc[48];
#pragma unroll
    for (int m = 0; m < 48; ++m) acc[m] = 0.f;
    const float* wbase = wT + woff + mh * 48;
#pragma unroll 4
    for (int c = 0; c < 96; ++c) {
        float v = in_lds[c][x];
        const float* wc = wbase + c * cstride;
#pragma unroll
        for (int m = 0; m < 48; ++m) acc[m] = fmaf(wc[m], v, acc[m]);
    }
    float* outb = out + (size_t)b * 96 * HWc + (size_t)(mh * 48) * HWc + px0 + x;
#pragma unroll
    for (int m = 0; m < 48; ++m) outb[(size_t)m * HWc] = acc[m];
}

// ---- depthwise 3x3 (pad=1) + per-channel sumsq ----
// Thread = 4-px x 8-row tile. Rolling 3-row register window, float4 loads,
// x-halo via __shfl from neighbor lanes (wave == one full 256-px row group).
__global__ __launch_bounds__(256) void depthwise3x3_kernel(
    const float* __restrict__ in, const float* __restrict__ wq,
    float* __restrict__ out, float* __restrict__ ssq_q)
{
    __shared__ float red[4];
    int c = blockIdx.y, b = blockIdx.z;
    int t = threadIdx.x;
    int lane = t & 63;
    int xq = lane * 4;                          // 0..252, wave spans full row
    int yb = blockIdx.x * 32 + (t >> 6) * 8;    // 4 row-groups of 8 per block

    const float* inc = in + ((size_t)(b * 96 + c)) * HWc;
    float* outc = out + ((size_t)(b * 96 + c)) * HWc;

    float w[9];
    const float* wp = wq + (size_t)c * 9;
#pragma unroll
    for (int i = 0; i < 9; ++i) w[i] = wp[i];

    float rows[3][6];

#define LOAD_ROW(yy, slot)                                                     \
    {                                                                          \
        float4 v_;                                                             \
        if ((unsigned)(yy) < (unsigned)Hd)                                     \
            v_ = *(const float4*)(inc + (size_t)(yy) * Wd + xq);               \
        else                                                                   \
            v_ = make_float4(0.f, 0.f, 0.f, 0.f);                              \
        float lw_ = __shfl_up(v_.w, 1, 64);                                    \
        float rx_ = __shfl_down(v_.x, 1, 64);                                  \
        rows[slot][0] = (lane > 0) ? lw_ : 0.f;                                \
        rows[slot][1] = v_.x; rows[slot][2] = v_.y;                            \
        rows[slot][3] = v_.z; rows[slot][4] = v_.w;                            \
        rows[slot][5] = (lane < 63) ? rx_ : 0.f;                               \
    }

    LOAD_ROW(yb - 1, 0);
    LOAD_ROW(yb, 1);

    float ssq = 0.f;
#pragma unroll
    for (int r = 0; r < 8; ++r) {
        LOAD_ROW(yb + r + 1, (r + 2) % 3);
        const float* ra = rows[r % 3];        // y-1
        const float* rb = rows[(r + 1) % 3];  // y
        const float* rc = rows[(r + 2) % 3];  // y+1
        float a[4] = {0.f, 0.f, 0.f, 0.f};
#pragma unroll
        for (int dx = 0; dx < 3; ++dx)
#pragma unroll
            for (int px = 0; px < 4; ++px) {
                a[px] = fmaf(w[dx],     ra[px + dx], a[px]);
                a[px] = fmaf(w[3 + dx], rb[px + dx], a[px]);
                a[px] = fmaf(w[6 + dx], rc[px + dx], a[px]);
            }
        *(float4*)(outc + (size_t)(yb + r) * Wd + xq) = *(float4*)a;
#pragma unroll
        for (int px = 0; px < 4; ++px) ssq = fmaf(a[px], a[px], ssq);
    }
#undef LOAD_ROW

    // block covers one channel: wave reduce -> LDS -> one atomic
#pragma unroll
    for (int off = 32; off; off >>= 1) ssq += __shfl_down(ssq, off, 64);
    int wvi = t >> 6;
    if (lane == 0) red[wvi] = ssq;
    __syncthreads();
    if (t == 0) atomicAdd(&ssq_q[b * 96 + c], red[0] + red[1] + red[2] + red[3]);
}

// ---- fused: grouped3x3(kmid) -> k row-tiles (LDS) + logits Gram + ssq_k ----
__global__ __launch_bounds__(256) void k_logits_kernel(
    const float* __restrict__ mid,   // kmid [b][96][HW]
    const float* __restrict__ w2,    // kvw2 [192][2][3][3]
    const float* __restrict__ qg,    // q [b][96][HW] (in d_out)
    float* __restrict__ attn_raw,    // [b][4][24][24]
    float* __restrict__ ssq_k)       // [b][96]
{
    __shared__ float qs[24][260];
    __shared__ float ks[24][260];

    int yt = blockIdx.x, h = blockIdx.y, b = blockIdx.z;
    int t = threadIdx.x, lane = t & 63, wvi = t >> 6;
    int i0 = (lane >> 3) * 3, j0 = (lane & 7) * 3;

    const float* midb = mid + ((size_t)b * 96 + h * 24) * HWc;
    const float* qb   = qg  + ((size_t)b * 96 + h * 24) * HWc;

    int p = t >> 4;
    float wv[36];
    if (t < 192) {
        const float* wp = w2 + (size_t)(h * 24 + 2 * p) * 18;
#pragma unroll
        for (int i = 0; i < 36; ++i) wv[i] = wp[i];
    }

    float acc[3][3];
#pragma unroll
    for (int a = 0; a < 3; ++a)
#pragma unroll
        for (int c2 = 0; c2 < 3; ++c2) acc[a][c2] = 0.f;
    float ssq0 = 0.f, ssq1 = 0.f;

    for (int r = 0; r < 8; ++r) {
        int y = yt * 8 + r;
        __syncthreads();

        if (t >= 192) {
            int u = t & 63;
            const float* qrow = qb + (size_t)y * Wd;
#pragma unroll
            for (int m = 0; m < 24; ++m) {
                int xo = u * 4;
                *(float4*)&qs[m][xo] = *(const float4*)(qrow + (size_t)m * HWc + xo);
            }
        } else {
            const float* m0 = midb + (size_t)(2 * p) * HWc;
            const float* m1 = m0 + HWc;
#pragma unroll
            for (int s = 0; s < 4; ++s) {
                int x0 = (t & 15) * 4 + s * 64;
                float k0[4] = {0.f, 0.f, 0.f, 0.f};
                float k1[4] = {0.f, 0.f, 0.f, 0.f};
#pragma unroll
                for (int dy = 0; dy < 3; ++dy) {
                    int yy = y + dy - 1;
                    if ((unsigned)yy < (unsigned)Hd) {
#pragma unroll
                        for (int ic = 0; ic < 2; ++ic) {
                            const float* base = (ic ? m1 : m0) + (size_t)yy * Wd;
                            float4 cv = *(const float4*)(base + x0);
                            float rr[6];
                            rr[0] = (x0 > 0) ? base[x0 - 1] : 0.f;
                            rr[1] = cv.x; rr[2] = cv.y; rr[3] = cv.z; rr[4] = cv.w;
                            rr[5] = (x0 < 252) ? base[x0 + 4] : 0.f;
                            int wb_ = ic * 9 + dy * 3;
#pragma unroll
                            for (int px = 0; px < 4; ++px) {
#pragma unroll
                                for (int dx = 0; dx < 3; ++dx) {
                                    k0[px] = fmaf(wv[wb_ + dx],      rr[px + dx], k0[px]);
                                    k1[px] = fmaf(wv[18 + wb_ + dx], rr[px + dx], k1[px]);
                                }
                            }
                        }
                    }
                }
#pragma unroll
                for (int px = 0; px < 4; ++px) {
                    ssq0 = fmaf(k0[px], k0[px], ssq0);
                    ssq1 = fmaf(k1[px], k1[px], ssq1);
                }
                *(float4*)&ks[2 * p][x0]     = *(float4*)k0;
                *(float4*)&ks[2 * p + 1][x0] = *(float4*)k1;
            }
        }
        __syncthreads();

        int n0 = wvi * 64;
#pragma unroll 4
        for (int nn = 0; nn < 16; ++nn) {
            int n = n0 + nn * 4;
            float4 q0v = *(const float4*)&qs[i0][n];
            float4 q1v = *(const float4*)&qs[i0 + 1][n];
            float4 q2v = *(const float4*)&qs[i0 + 2][n];
            float4 k0v = *(const float4*)&ks[j0][n];
            float4 k1v = *(const float4*)&ks[j0 + 1][n];
            float4 k2v = *(const float4*)&ks[j0 + 2][n];
            acc[0][0] += q0v.x*k0v.x + q0v.y*k0v.y + q0v.z*k0v.z + q0v.w*k0v.w;
            acc[0][1] += q0v.x*k1v.x + q0v.y*k1v.y + q0v.z*k1v.z + q0v.w*k1v.w;
            acc[0][2] += q0v.x*k2v.x + q0v.y*k2v.y + q0v.z*k2v.z + q0v.w*k2v.w;
            acc[1][0] += q1v.x*k0v.x + q1v.y*k0v.y + q1v.z*k0v.z + q1v.w*k0v.w;
            acc[1][1] += q1v.x*k1v.x + q1v.y*k1v.y + q1v.z*k1v.z + q1v.w*k1v.w;
            acc[1][2] += q1v.x*k2v.x + q1v.y*k2v.y + q1v.z*k2v.z + q1v.w*k2v.w;
            acc[2][0] += q2v.x*k0v.x + q2v.y*k0v.y + q2v.z*k0v.z + q2v.w*k0v.w;
            acc[2][1] += q2v.x*k1v.x + q2v.y*k1v.y + q2v.z*k1v.z + q2v.w*k1v.w;
            acc[2][2] += q2v.x*k2v.x + q2v.y*k2v.y + q2v.z*k2v.z + q2v.w*k2v.w;
        }
    }

    if (t < 192) {
        float s0 = ssq0, s1 = ssq1;
#pragma unroll
        for (int off = 8; off; off >>= 1) {
            s0 += __shfl_down(s0, off, 64);
            s1 += __shfl_down(s1, off, 64);
        }
        if ((t & 15) == 0) {
            atomicAdd(&ssq_k[b * 96 + h * 24 + 2 * p],     s0);
            atomicAdd(&ssq_k[b * 96 + h * 24 + 2 * p + 1], s1);
        }
    }

    __syncthreads();
    float* redbuf = &qs[0][0];
#pragma unroll
    for (int a = 0; a < 3; ++a)
#pragma unroll
        for (int c2 = 0; c2 < 3; ++c2)
            redbuf[wvi * 576 + (i0 + a) * 24 + (j0 + c2)] = acc[a][c2];
    __syncthreads();
    for (int p_ = t; p_ < 576; p_ += 256) {
        float s4 = redbuf[p_] + redbuf[576 + p_] + redbuf[1152 + p_] + redbuf[1728 + p_];
        atomicAdd(&attn_raw[((size_t)b * 4 + h) * 576 + p_], s4);
    }
}

// ---- softmax (+temperature, +1/(|q||k|)) then fold proj_w -> W2T[b][dv][co] ----
__global__ __launch_bounds__(256) void softmax_fold_kernel(
    const float* __restrict__ attn_raw,
    const float* __restrict__ ssq_q, const float* __restrict__ ssq_k,
    const float* __restrict__ temp, const float* __restrict__ projw,
    float* __restrict__ W2T)
{
    __shared__ float s[24][25];
    __shared__ float rq[24], rk[24];
    int h = blockIdx.x, b = blockIdx.y;
    int t = threadIdx.x;

    if (t < 24) {
        rq[t] = 1.f / fmaxf(sqrtf(ssq_q[b * 96 + h * 24 + t]), 1e-12f);
        rk[t] = 1.f / fmaxf(sqrtf(ssq_k[b * 96 + h * 24 + t]), 1e-12f);
    }
    __syncthreads();
    float T = temp[h];
    for (int p = t; p < 576; p += 256) {
        int i = p / 24, j = p % 24;
        s[i][j] = attn_raw[(size_t)(b * 4 + h) * 576 + p] * T * rq[i] * rk[j];
    }
    __syncthreads();
    if (t < 24) {
        float m = -1e30f;
#pragma unroll
        for (int j = 0; j < 24; ++j) m = fmaxf(m, s[t][j]);
        float sum = 0.f;
#pragma unroll
        for (int j = 0; j < 24; ++j) { float e = __expf(s[t][j] - m); s[t][j] = e; sum += e; }
        float inv = 1.f / sum;
#pragma unroll
        for (int j = 0; j < 24; ++j) s[t][j] *= inv;
    }
    __syncthreads();
    for (int m_ = t; m_ < 96 * 24; m_ += 256) {
        int d = m_ % 24, co = m_ / 24;
        float acc = 0.f;
#pragma unroll
        for (int c = 0; c < 24; ++c)
            acc += projw[co * 96 + h * 24 + c] * s[c][d];
        W2T[(size_t)b * 9216 + (size_t)(h * 24 + d) * 96 + co] = acc;
    }
}

// ---- fused: grouped3x3(vmid) -> v (regs) + out = W2 . v ----
__global__ __launch_bounds__(256) void v_proj_kernel(
    const float* __restrict__ mid, const float* __restrict__ w2,
    const float* __restrict__ W2T, float* __restrict__ out)
{
    int y = blockIdx.x, b = blockIdx.y;
    int x = threadIdx.x;
    const float* midb = mid + (size_t)b * 96 * HWc;
    const float* wfold = W2T + (size_t)b * 9216;

    float acc[96];
#pragma unroll
    for (int m = 0; m < 96; ++m) acc[m] = 0.f;

#pragma unroll 1
    for (int g = 0; g < 48; ++g) {
        const float* m0 = midb + (size_t)(2 * g) * HWc;
        const float* m1 = m0 + HWc;
        const float* wg = w2 + (size_t)(96 + 2 * g) * 18;
        float v0 = 0.f, v1 = 0.f;
#pragma unroll
        for (int dy = 0; dy < 3; ++dy) {
            int yy = y + dy - 1;
            if ((unsigned)yy < (unsigned)Hd) {
                const float* r0 = m0 + (size_t)yy * Wd;
                const float* r1 = m1 + (size_t)yy * Wd;
#pragma unroll
                for (int dx = 0; dx < 3; ++dx) {
                    int xx = x + dx - 1;
                    if ((unsigned)xx < (unsigned)Wd) {
                        float a0 = r0[xx], a1 = r1[xx];
                        v0 += wg[dy * 3 + dx] * a0 + wg[9  + dy * 3 + dx] * a1;
                        v1 += wg[18 + dy * 3 + dx] * a0 + wg[27 + dy * 3 + dx] * a1;
                    }
                }
            }
        }
        const float* f0 = wfold + (size_t)(2 * g) * 96;
        const float* f1 = f0 + 96;
#pragma unroll
        for (int m = 0; m < 96; ++m)
            acc[m] += f0[m] * v0 + f1[m] * v1;
    }
    float* outb = out + (size_t)b * 96 * HWc + (size_t)y * Wd + x;
#pragma unroll
    for (int m = 0; m < 96; ++m) outb[(size_t)m * HWc] = acc[m];
}

extern "C" void kernel_launch(void* const* d_in, const int* in_sizes, int n_in,
                              void* d_out, int out_size, void* d_ws, size_t ws_size,
                              hipStream_t stream) {
    const float* x     = (const float*)d_in[0];
    const float* z     = (const float*)d_in[1];
    const float* kvw1  = (const float*)d_in[2];
    const float* kvw2  = (const float*)d_in[3];
    const float* qw1   = (const float*)d_in[4];
    const float* qw2   = (const float*)d_in[5];
    const float* projw = (const float*)d_in[6];
    const float* temp  = (const float*)d_in[7];
    float* out = (float*)d_out;
    float* ws  = (float*)d_ws;
    (void)in_sizes; (void)n_in; (void)out_size; (void)ws_size;

    float* ssq_q = ws + SSQ_Q_OFF;
    float* ssq_k = ws + SSQ_K_OFF;
    float* attn  = ws + ATTN_OFF;
    float* W2T   = ws + W2T_OFF;
    float* kvw1T = ws + KVW1T_OFF;
    float* qw1T  = ws + QW1T_OFF;
    float* ws1   = ws + WS1_OFF;

    hipMemsetAsync(ws, 0, (768 + 768 + 18432) * sizeof(float), stream);

    transpose_w_kernel<<<dim3(72), 256, 0, stream>>>(kvw1, kvw1T, 192, 96);
    transpose_w_kernel<<<dim3(36), 256, 0, stream>>>(qw1, qw1T, 96, 96);

    // ---- q path ----
    conv1x1_lds<<<dim3(512, 8), 256, 0, stream>>>(x, qw1T, 96, 0, ws1);              // q1
    depthwise3x3_kernel<<<dim3(8, 96, 8), 256, 0, stream>>>(ws1, qw2, out, ssq_q);   // q

    // ---- k path ----
    conv1x1_lds<<<dim3(512, 8), 256, 0, stream>>>(z, kvw1T, 192, 0, ws1);            // kmid
    k_logits_kernel<<<dim3(32, 4, 8), 256, 0, stream>>>(ws1, kvw2, out, attn, ssq_k);

    softmax_fold_kernel<<<dim3(4, 8), 256, 0, stream>>>(attn, ssq_q, ssq_k, temp, projw, W2T);

    // ---- v path ----
    conv1x1_lds<<<dim3(512, 8), 256, 0, stream>>>(z, kvw1T, 192, 96, ws1);           // vmid
    v_proj_kernel<<<dim3(256, 8), 256, 0, stream>>>(ws1, kvw2, W2T, out);
}

// Round 5
// 1291.038 us; speedup vs baseline: 2.4033x; 1.0696x over previous
//
#include <hip/hip_runtime.h>
#include <math.h>

#define HWc 65536
#define Wd 256
#define Hd 256

// ---- ws layout (float offsets), small buffers FIRST ----
static const size_t SSQ_Q_OFF = 0;        // 768
static const size_t SSQ_K_OFF = 768;      // 768
static const size_t ATTN_OFF  = 1536;     // 8*4*576 = 18432
static const size_t W2T_OFF   = 19968;    // 8*96*96 = 73728
static const size_t KVW1T_OFF = 93696;    // 96*192 = 18432
static const size_t QW1T_OFF  = 112128;   // 96*96 = 9216
static const size_t WS1_OFF   = 121344;   // 8*96*HWc = 50331648 floats (201 MB)

// ---- transpose [O][I] -> [I][O] ----
__global__ void transpose_w_kernel(const float* __restrict__ w, float* __restrict__ wT,
                                   int O, int I) {
    int idx = blockIdx.x * 256 + threadIdx.x;
    if (idx < O * I) {
        int o = idx / I, c = idx % I;
        wT[(size_t)c * O + o] = w[idx];
    }
}

// ---- 1x1 conv via LDS staging: block = 128 px, stage in[96][128] once ----
__global__ __launch_bounds__(256) void conv1x1_lds(
    const float* __restrict__ in, const float* __restrict__ wT,
    int cstride, int woff, float* __restrict__ out)
{
    __shared__ float in_lds[96][128];
    int b = blockIdx.y;
    int px0 = blockIdx.x * 128;
    int t = threadIdx.x;
    const float* inb = in + (size_t)b * 96 * HWc + px0;

#pragma unroll
    for (int m = 0; m < 12; ++m) {
        int fi = m * 256 + t;
        int c = fi >> 5;
        int xo = (fi & 31) * 4;
        *(float4*)&in_lds[c][xo] = *(const float4*)(inb + (size_t)c * HWc + xo);
    }
    __syncthreads();

    int x = t & 127;
    int mh = __builtin_amdgcn_readfirstlane(t >> 7);
    float acc[48];
#pragma unroll
    for (int m = 0; m < 48; ++m) acc[m] = 0.f;
    const float* wbase = wT + woff + mh * 48;
#pragma unroll 4
    for (int c = 0; c < 96; ++c) {
        float v = in_lds[c][x];
        const float* wc = wbase + c * cstride;
#pragma unroll
        for (int m = 0; m < 48; ++m) acc[m] = fmaf(wc[m], v, acc[m]);
    }
    float* outb = out + (size_t)b * 96 * HWc + (size_t)(mh * 48) * HWc + px0 + x;
#pragma unroll
    for (int m = 0; m < 48; ++m) outb[(size_t)m * HWc] = acc[m];
}

// ---- depthwise 3x3 (pad=1) + per-channel sumsq ----
__global__ __launch_bounds__(256) void depthwise3x3_kernel(
    const float* __restrict__ in, const float* __restrict__ wq,
    float* __restrict__ out, float* __restrict__ ssq_q)
{
    __shared__ float red[4];
    int c = blockIdx.y, b = blockIdx.z;
    int t = threadIdx.x;
    int lane = t & 63;
    int xq = lane * 4;
    int yb = blockIdx.x * 32 + (t >> 6) * 8;

    const float* inc = in + ((size_t)(b * 96 + c)) * HWc;
    float* outc = out + ((size_t)(b * 96 + c)) * HWc;

    float w[9];
    const float* wp = wq + (size_t)c * 9;
#pragma unroll
    for (int i = 0; i < 9; ++i) w[i] = wp[i];

    float rows[3][6];

#define LOAD_ROW(yy, slot)                                                     \
    {                                                                          \
        float4 v_;                                                             \
        if ((unsigned)(yy) < (unsigned)Hd)                                     \
            v_ = *(const float4*)(inc + (size_t)(yy) * Wd + xq);               \
        else                                                                   \
            v_ = make_float4(0.f, 0.f, 0.f, 0.f);                              \
        float lw_ = __shfl_up(v_.w, 1, 64);                                    \
        float rx_ = __shfl_down(v_.x, 1, 64);                                  \
        rows[slot][0] = (lane > 0) ? lw_ : 0.f;                                \
        rows[slot][1] = v_.x; rows[slot][2] = v_.y;                            \
        rows[slot][3] = v_.z; rows[slot][4] = v_.w;                            \
        rows[slot][5] = (lane < 63) ? rx_ : 0.f;                               \
    }

    LOAD_ROW(yb - 1, 0);
    LOAD_ROW(yb, 1);

    float ssq = 0.f;
#pragma unroll
    for (int r = 0; r < 8; ++r) {
        LOAD_ROW(yb + r + 1, (r + 2) % 3);
        const float* ra = rows[r % 3];
        const float* rb = rows[(r + 1) % 3];
        const float* rc = rows[(r + 2) % 3];
        float a[4] = {0.f, 0.f, 0.f, 0.f};
#pragma unroll
        for (int dx = 0; dx < 3; ++dx)
#pragma unroll
            for (int px = 0; px < 4; ++px) {
                a[px] = fmaf(w[dx],     ra[px + dx], a[px]);
                a[px] = fmaf(w[3 + dx], rb[px + dx], a[px]);
                a[px] = fmaf(w[6 + dx], rc[px + dx], a[px]);
            }
        *(float4*)(outc + (size_t)(yb + r) * Wd + xq) = *(float4*)a;
#pragma unroll
        for (int px = 0; px < 4; ++px) ssq = fmaf(a[px], a[px], ssq);
    }
#undef LOAD_ROW

#pragma unroll
    for (int off = 32; off; off >>= 1) ssq += __shfl_down(ssq, off, 64);
    int wvi = t >> 6;
    if (lane == 0) red[wvi] = ssq;
    __syncthreads();
    if (t == 0) atomicAdd(&ssq_q[b * 96 + c], red[0] + red[1] + red[2] + red[3]);
}

// ---- fused: grouped3x3(kmid) -> k row-tiles (LDS) + logits Gram + ssq_k ----
__global__ __launch_bounds__(256) void k_logits_kernel(
    const float* __restrict__ mid, const float* __restrict__ w2,
    const float* __restrict__ qg, float* __restrict__ attn_raw,
    float* __restrict__ ssq_k)
{
    __shared__ float qs[24][260];
    __shared__ float ks[24][260];

    int yt = blockIdx.x, h = blockIdx.y, b = blockIdx.z;
    int t = threadIdx.x, lane = t & 63, wvi = t >> 6;
    int i0 = (lane >> 3) * 3, j0 = (lane & 7) * 3;

    const float* midb = mid + ((size_t)b * 96 + h * 24) * HWc;
    const float* qb   = qg  + ((size_t)b * 96 + h * 24) * HWc;

    int p = t >> 4;
    float wv[36];
    if (t < 192) {
        const float* wp = w2 + (size_t)(h * 24 + 2 * p) * 18;
#pragma unroll
        for (int i = 0; i < 36; ++i) wv[i] = wp[i];
    }

    float acc[3][3];
#pragma unroll
    for (int a = 0; a < 3; ++a)
#pragma unroll
        for (int c2 = 0; c2 < 3; ++c2) acc[a][c2] = 0.f;
    float ssq0 = 0.f, ssq1 = 0.f;

    for (int r = 0; r < 8; ++r) {
        int y = yt * 8 + r;
        __syncthreads();

        if (t >= 192) {
            int u = t & 63;
            const float* qrow = qb + (size_t)y * Wd;
#pragma unroll
            for (int m = 0; m < 24; ++m) {
                int xo = u * 4;
                *(float4*)&qs[m][xo] = *(const float4*)(qrow + (size_t)m * HWc + xo);
            }
        } else {
            const float* m0 = midb + (size_t)(2 * p) * HWc;
            const float* m1 = m0 + HWc;
#pragma unroll
            for (int s = 0; s < 4; ++s) {
                int x0 = (t & 15) * 4 + s * 64;
                float k0[4] = {0.f, 0.f, 0.f, 0.f};
                float k1[4] = {0.f, 0.f, 0.f, 0.f};
#pragma unroll
                for (int dy = 0; dy < 3; ++dy) {
                    int yy = y + dy - 1;
                    if ((unsigned)yy < (unsigned)Hd) {
#pragma unroll
                        for (int ic = 0; ic < 2; ++ic) {
                            const float* base = (ic ? m1 : m0) + (size_t)yy * Wd;
                            float4 cv = *(const float4*)(base + x0);
                            float rr[6];
                            rr[0] = (x0 > 0) ? base[x0 - 1] : 0.f;
                            rr[1] = cv.x; rr[2] = cv.y; rr[3] = cv.z; rr[4] = cv.w;
                            rr[5] = (x0 < 252) ? base[x0 + 4] : 0.f;
                            int wb_ = ic * 9 + dy * 3;
#pragma unroll
                            for (int px = 0; px < 4; ++px) {
#pragma unroll
                                for (int dx = 0; dx < 3; ++dx) {
                                    k0[px] = fmaf(wv[wb_ + dx],      rr[px + dx], k0[px]);
                                    k1[px] = fmaf(wv[18 + wb_ + dx], rr[px + dx], k1[px]);
                                }
                            }
                        }
                    }
                }
#pragma unroll
                for (int px = 0; px < 4; ++px) {
                    ssq0 = fmaf(k0[px], k0[px], ssq0);
                    ssq1 = fmaf(k1[px], k1[px], ssq1);
                }
                *(float4*)&ks[2 * p][x0]     = *(float4*)k0;
                *(float4*)&ks[2 * p + 1][x0] = *(float4*)k1;
            }
        }
        __syncthreads();

        int n0 = wvi * 64;
#pragma unroll 4
        for (int nn = 0; nn < 16; ++nn) {
            int n = n0 + nn * 4;
            float4 q0v = *(const float4*)&qs[i0][n];
            float4 q1v = *(const float4*)&qs[i0 + 1][n];
            float4 q2v = *(const float4*)&qs[i0 + 2][n];
            float4 k0v = *(const float4*)&ks[j0][n];
            float4 k1v = *(const float4*)&ks[j0 + 1][n];
            float4 k2v = *(const float4*)&ks[j0 + 2][n];
            acc[0][0] += q0v.x*k0v.x + q0v.y*k0v.y + q0v.z*k0v.z + q0v.w*k0v.w;
            acc[0][1] += q0v.x*k1v.x + q0v.y*k1v.y + q0v.z*k1v.z + q0v.w*k1v.w;
            acc[0][2] += q0v.x*k2v.x + q0v.y*k2v.y + q0v.z*k2v.z + q0v.w*k2v.w;
            acc[1][0] += q1v.x*k0v.x + q1v.y*k0v.y + q1v.z*k0v.z + q1v.w*k0v.w;
            acc[1][1] += q1v.x*k1v.x + q1v.y*k1v.y + q1v.z*k1v.z + q1v.w*k1v.w;
            acc[1][2] += q1v.x*k2v.x + q1v.y*k2v.y + q1v.z*k2v.z + q1v.w*k2v.w;
            acc[2][0] += q2v.x*k0v.x + q2v.y*k0v.y + q2v.z*k0v.z + q2v.w*k0v.w;
            acc[2][1] += q2v.x*k1v.x + q2v.y*k1v.y + q2v.z*k1v.z + q2v.w*k1v.w;
            acc[2][2] += q2v.x*k2v.x + q2v.y*k2v.y + q2v.z*k2v.z + q2v.w*k2v.w;
        }
    }

    if (t < 192) {
        float s0 = ssq0, s1 = ssq1;
#pragma unroll
        for (int off = 8; off; off >>= 1) {
            s0 += __shfl_down(s0, off, 64);
            s1 += __shfl_down(s1, off, 64);
        }
        if ((t & 15) == 0) {
            atomicAdd(&ssq_k[b * 96 + h * 24 + 2 * p],     s0);
            atomicAdd(&ssq_k[b * 96 + h * 24 + 2 * p + 1], s1);
        }
    }

    __syncthreads();
    float* redbuf = &qs[0][0];
#pragma unroll
    for (int a = 0; a < 3; ++a)
#pragma unroll
        for (int c2 = 0; c2 < 3; ++c2)
            redbuf[wvi * 576 + (i0 + a) * 24 + (j0 + c2)] = acc[a][c2];
    __syncthreads();
    for (int p_ = t; p_ < 576; p_ += 256) {
        float s4 = redbuf[p_] + redbuf[576 + p_] + redbuf[1152 + p_] + redbuf[1728 + p_];
        atomicAdd(&attn_raw[((size_t)b * 4 + h) * 576 + p_], s4);
    }
}

// ---- softmax (+temperature, +1/(|q||k|)) then fold proj_w -> W2T[b][dv][co] ----
__global__ __launch_bounds__(256) void softmax_fold_kernel(
    const float* __restrict__ attn_raw,
    const float* __restrict__ ssq_q, const float* __restrict__ ssq_k,
    const float* __restrict__ temp, const float* __restrict__ projw,
    float* __restrict__ W2T)
{
    __shared__ float s[24][25];
    __shared__ float rq[24], rk[24];
    int h = blockIdx.x, b = blockIdx.y;
    int t = threadIdx.x;

    if (t < 24) {
        rq[t] = 1.f / fmaxf(sqrtf(ssq_q[b * 96 + h * 24 + t]), 1e-12f);
        rk[t] = 1.f / fmaxf(sqrtf(ssq_k[b * 96 + h * 24 + t]), 1e-12f);
    }
    __syncthreads();
    float T = temp[h];
    for (int p = t; p < 576; p += 256) {
        int i = p / 24, j = p % 24;
        s[i][j] = attn_raw[(size_t)(b * 4 + h) * 576 + p] * T * rq[i] * rk[j];
    }
    __syncthreads();
    if (t < 24) {
        float m = -1e30f;
#pragma unroll
        for (int j = 0; j < 24; ++j) m = fmaxf(m, s[t][j]);
        float sum = 0.f;
#pragma unroll
        for (int j = 0; j < 24; ++j) { float e = __expf(s[t][j] - m); s[t][j] = e; sum += e; }
        float inv = 1.f / sum;
#pragma unroll
        for (int j = 0; j < 24; ++j) s[t][j] *= inv;
    }
    __syncthreads();
    for (int m_ = t; m_ < 96 * 24; m_ += 256) {
        int d = m_ % 24, co = m_ / 24;
        float acc = 0.f;
#pragma unroll
        for (int c = 0; c < 24; ++c)
            acc += projw[co * 96 + h * 24 + c] * s[c][d];
        W2T[(size_t)b * 9216 + (size_t)(h * 24 + d) * 96 + co] = acc;
    }
}

// ---- fused: grouped3x3(vmid) -> v_lds tile + GEMM out = W2 . v ----
// block = one 128-px row tile. Phase 1: stage v-weights in LDS. Phase 2: compute
// v_lds[96][132] (thread = fixed 4-px strip, pairs 8j+(t>>5), f4 loads + edge
// scalars). Phase 3: conv1x1-style GEMM with s_load W2T weights.
__global__ __launch_bounds__(256) void v_proj_kernel(
    const float* __restrict__ mid, const float* __restrict__ w2,
    const float* __restrict__ W2T, float* __restrict__ out)
{
    __shared__ float v_lds[96][132];
    __shared__ float wls[48 * 36];

    int bx = blockIdx.x, b = blockIdx.y;
    int y = bx >> 1;
    int x0 = (bx & 1) * 128;
    int t = threadIdx.x;
    const float* midb = mid + (size_t)b * 96 * HWc;

    // phase 1: stage v-weights (channels 96..191 of w2): 1728 floats = 432 f4
    {
        const float* vw = w2 + 96 * 18;
        for (int i = t; i < 432; i += 256)
            *(float4*)&wls[4 * i] = *(const float4*)(vw + 4 * i);
    }
    __syncthreads();

    // phase 2: compute v tile
    {
        int s4 = (t & 31) * 4;       // strip within tile, fixed per thread
        int xg = x0 + s4;            // global x of first px
#pragma unroll
        for (int j = 0; j < 6; ++j) {
            int pair = j * 8 + (t >> 5);           // per-thread constant
            const float* m0 = midb + (size_t)(2 * pair) * HWc;
            const float* m1 = m0 + HWc;
            const float* wp_ = &wls[pair * 36];    // 32-lane broadcast reads
            float k0[4] = {0.f, 0.f, 0.f, 0.f};
            float k1[4] = {0.f, 0.f, 0.f, 0.f};
#pragma unroll
            for (int dy = 0; dy < 3; ++dy) {
                int yy = y + dy - 1;
                if ((unsigned)yy < (unsigned)Hd) {   // block-uniform
#pragma unroll
                    for (int ic = 0; ic < 2; ++ic) {
                        const float* base = (ic ? m1 : m0) + (size_t)yy * Wd;
                        float4 cv = *(const float4*)(base + xg);
                        float rr[6];
                        rr[0] = (xg > 0) ? base[xg - 1] : 0.f;
                        rr[1] = cv.x; rr[2] = cv.y; rr[3] = cv.z; rr[4] = cv.w;
                        rr[5] = (xg < 252) ? base[xg + 4] : 0.f;
                        int wb_ = ic * 9 + dy * 3;
#pragma unroll
                        for (int px = 0; px < 4; ++px) {
#pragma unroll
                            for (int dx = 0; dx < 3; ++dx) {
                                k0[px] = fmaf(wp_[wb_ + dx],      rr[px + dx], k0[px]);
                                k1[px] = fmaf(wp_[18 + wb_ + dx], rr[px + dx], k1[px]);
                            }
                        }
                    }
                }
            }
            *(float4*)&v_lds[2 * pair][s4]     = *(float4*)k0;
            *(float4*)&v_lds[2 * pair + 1][s4] = *(float4*)k1;
        }
    }
    __syncthreads();

    // phase 3: GEMM — half-block covers 128 px x 48 out channels
    int x = t & 127;
    int mh = __builtin_amdgcn_readfirstlane(t >> 7);
    float acc[48];
#pragma unroll
    for (int m = 0; m < 48; ++m) acc[m] = 0.f;
    const float* wb2 = W2T + (size_t)b * 9216 + mh * 48;
#pragma unroll 4
    for (int c = 0; c < 96; ++c) {
        float v = v_lds[c][x];
        const float* wc = wb2 + c * 96;
#pragma unroll
        for (int m = 0; m < 48; ++m) acc[m] = fmaf(wc[m], v, acc[m]);
    }
    float* outb = out + (size_t)b * 96 * HWc + (size_t)(mh * 48) * HWc
                + (size_t)y * Wd + x0 + x;
#pragma unroll
    for (int m = 0; m < 48; ++m) outb[(size_t)m * HWc] = acc[m];
}

extern "C" void kernel_launch(void* const* d_in, const int* in_sizes, int n_in,
                              void* d_out, int out_size, void* d_ws, size_t ws_size,
                              hipStream_t stream) {
    const float* x     = (const float*)d_in[0];
    const float* z     = (const float*)d_in[1];
    const float* kvw1  = (const float*)d_in[2];
    const float* kvw2  = (const float*)d_in[3];
    const float* qw1   = (const float*)d_in[4];
    const float* qw2   = (const float*)d_in[5];
    const float* projw = (const float*)d_in[6];
    const float* temp  = (const float*)d_in[7];
    float* out = (float*)d_out;
    float* ws  = (float*)d_ws;
    (void)in_sizes; (void)n_in; (void)out_size; (void)ws_size;

    float* ssq_q = ws + SSQ_Q_OFF;
    float* ssq_k = ws + SSQ_K_OFF;
    float* attn  = ws + ATTN_OFF;
    float* W2T   = ws + W2T_OFF;
    float* kvw1T = ws + KVW1T_OFF;
    float* qw1T  = ws + QW1T_OFF;
    float* ws1   = ws + WS1_OFF;

    hipMemsetAsync(ws, 0, (768 + 768 + 18432) * sizeof(float), stream);

    transpose_w_kernel<<<dim3(72), 256, 0, stream>>>(kvw1, kvw1T, 192, 96);
    transpose_w_kernel<<<dim3(36), 256, 0, stream>>>(qw1, qw1T, 96, 96);

    // ---- q path ----
    conv1x1_lds<<<dim3(512, 8), 256, 0, stream>>>(x, qw1T, 96, 0, ws1);              // q1
    depthwise3x3_kernel<<<dim3(8, 96, 8), 256, 0, stream>>>(ws1, qw2, out, ssq_q);   // q

    // ---- k path ----
    conv1x1_lds<<<dim3(512, 8), 256, 0, stream>>>(z, kvw1T, 192, 0, ws1);            // kmid
    k_logits_kernel<<<dim3(32, 4, 8), 256, 0, stream>>>(ws1, kvw2, out, attn, ssq_k);

    softmax_fold_kernel<<<dim3(4, 8), 256, 0, stream>>>(attn, ssq_q, ssq_k, temp, projw, W2T);

    // ---- v path ----
    conv1x1_lds<<<dim3(512, 8), 256, 0, stream>>>(z, kvw1T, 192, 96, ws1);           // vmid
    v_proj_kernel<<<dim3(512, 8), 256, 0, stream>>>(ws1, kvw2, W2T, out);
}

// Round 6
// 994.335 us; speedup vs baseline: 3.1204x; 1.2984x over previous
//
#include <hip/hip_runtime.h>
#include <math.h>

#define HWc 65536
#define Wd 256
#define Hd 256

// ---- ws layout (float offsets), small buffers FIRST ----
static const size_t SSQ_Q_OFF = 0;        // 768
static const size_t SSQ_K_OFF = 768;      // 768
static const size_t ATTN_OFF  = 1536;     // 8*4*576 = 18432
static const size_t W2T_OFF   = 19968;    // 8*96*96 = 73728
static const size_t KVW1T_OFF = 93696;    // 96*192 = 18432
static const size_t QW1T_OFF  = 112128;   // 96*96 = 9216
static const size_t WS1_OFF   = 121344;   // 8*96*HWc = 50331648 floats (201 MB)

// ---- transpose [O][I] -> [I][O] ----
__global__ void transpose_w_kernel(const float* __restrict__ w, float* __restrict__ wT,
                                   int O, int I) {
    int idx = blockIdx.x * 256 + threadIdx.x;
    if (idx < O * I) {
        int o = idx / I, c = idx % I;
        wT[(size_t)c * O + o] = w[idx];
    }
}

// ---- 1x1 conv, LDS channel-split: stage in[48][128] twice (32->24.5KB LDS) ----
__global__ __launch_bounds__(256) void conv1x1_lds(
    const float* __restrict__ in, const float* __restrict__ wT,
    int cstride, int woff, float* __restrict__ out)
{
    __shared__ float in_lds[48][128];
    int b = blockIdx.y;
    int px0 = blockIdx.x * 128;
    int t = threadIdx.x;
    const float* inb = in + (size_t)b * 96 * HWc + px0;

    int x = t & 127;
    int mh = __builtin_amdgcn_readfirstlane(t >> 7);
    const float* wbase = wT + woff + mh * 48;
    float acc[48];
#pragma unroll
    for (int m = 0; m < 48; ++m) acc[m] = 0.f;

#pragma unroll 1
    for (int half = 0; half < 2; ++half) {
        __syncthreads();   // protect LDS from previous phase's readers
#pragma unroll
        for (int m = 0; m < 6; ++m) {
            int fi = m * 256 + t;
            int c = fi >> 5;
            int xo = (fi & 31) * 4;
            *(float4*)&in_lds[c][xo] =
                *(const float4*)(inb + (size_t)(half * 48 + c) * HWc + xo);
        }
        __syncthreads();
        const float* wb2 = wbase + (size_t)(half * 48) * cstride;
#pragma unroll 4
        for (int c = 0; c < 48; ++c) {
            float v = in_lds[c][x];
            const float* wc = wb2 + c * cstride;
#pragma unroll
            for (int m = 0; m < 48; ++m) acc[m] = fmaf(wc[m], v, acc[m]);
        }
    }
    float* outb = out + (size_t)b * 96 * HWc + (size_t)(mh * 48) * HWc + px0 + x;
#pragma unroll
    for (int m = 0; m < 48; ++m) outb[(size_t)m * HWc] = acc[m];
}

// ---- depthwise 3x3 (pad=1) + per-channel sumsq ----
__global__ __launch_bounds__(256) void depthwise3x3_kernel(
    const float* __restrict__ in, const float* __restrict__ wq,
    float* __restrict__ out, float* __restrict__ ssq_q)
{
    __shared__ float red[4];
    int c = blockIdx.y, b = blockIdx.z;
    int t = threadIdx.x;
    int lane = t & 63;
    int xq = lane * 4;
    int yb = blockIdx.x * 32 + (t >> 6) * 8;

    const float* inc = in + ((size_t)(b * 96 + c)) * HWc;
    float* outc = out + ((size_t)(b * 96 + c)) * HWc;

    float w[9];
    const float* wp = wq + (size_t)c * 9;
#pragma unroll
    for (int i = 0; i < 9; ++i) w[i] = wp[i];

    float rows[3][6];

#define LOAD_ROW(yy, slot)                                                     \
    {                                                                          \
        float4 v_;                                                             \
        if ((unsigned)(yy) < (unsigned)Hd)                                     \
            v_ = *(const float4*)(inc + (size_t)(yy) * Wd + xq);               \
        else                                                                   \
            v_ = make_float4(0.f, 0.f, 0.f, 0.f);                              \
        float lw_ = __shfl_up(v_.w, 1, 64);                                    \
        float rx_ = __shfl_down(v_.x, 1, 64);                                  \
        rows[slot][0] = (lane > 0) ? lw_ : 0.f;                                \
        rows[slot][1] = v_.x; rows[slot][2] = v_.y;                            \
        rows[slot][3] = v_.z; rows[slot][4] = v_.w;                            \
        rows[slot][5] = (lane < 63) ? rx_ : 0.f;                               \
    }

    LOAD_ROW(yb - 1, 0);
    LOAD_ROW(yb, 1);

    float ssq = 0.f;
#pragma unroll
    for (int r = 0; r < 8; ++r) {
        LOAD_ROW(yb + r + 1, (r + 2) % 3);
        const float* ra = rows[r % 3];
        const float* rb = rows[(r + 1) % 3];
        const float* rc = rows[(r + 2) % 3];
        float a[4] = {0.f, 0.f, 0.f, 0.f};
#pragma unroll
        for (int dx = 0; dx < 3; ++dx)
#pragma unroll
            for (int px = 0; px < 4; ++px) {
                a[px] = fmaf(w[dx],     ra[px + dx], a[px]);
                a[px] = fmaf(w[3 + dx], rb[px + dx], a[px]);
                a[px] = fmaf(w[6 + dx], rc[px + dx], a[px]);
            }
        *(float4*)(outc + (size_t)(yb + r) * Wd + xq) = *(float4*)a;
#pragma unroll
        for (int px = 0; px < 4; ++px) ssq = fmaf(a[px], a[px], ssq);
    }
#undef LOAD_ROW

#pragma unroll
    for (int off = 32; off; off >>= 1) ssq += __shfl_down(ssq, off, 64);
    int wvi = t >> 6;
    if (lane == 0) red[wvi] = ssq;
    __syncthreads();
    if (t == 0) atomicAdd(&ssq_q[b * 96 + c], red[0] + red[1] + red[2] + red[3]);
}

// ---- fused: grouped3x3(kmid) -> k row-tiles (LDS) + logits Gram + ssq_k ----
__global__ __launch_bounds__(256) void k_logits_kernel(
    const float* __restrict__ mid, const float* __restrict__ w2,
    const float* __restrict__ qg, float* __restrict__ attn_raw,
    float* __restrict__ ssq_k)
{
    __shared__ float qs[24][260];
    __shared__ float ks[24][260];

    int yt = blockIdx.x, h = blockIdx.y, b = blockIdx.z;
    int t = threadIdx.x, lane = t & 63, wvi = t >> 6;
    int i0 = (lane >> 3) * 3, j0 = (lane & 7) * 3;

    const float* midb = mid + ((size_t)b * 96 + h * 24) * HWc;
    const float* qb   = qg  + ((size_t)b * 96 + h * 24) * HWc;

    int p = t >> 4;
    float wv[36];
    if (t < 192) {
        const float* wp = w2 + (size_t)(h * 24 + 2 * p) * 18;
#pragma unroll
        for (int i = 0; i < 36; ++i) wv[i] = wp[i];
    }

    float acc[3][3];
#pragma unroll
    for (int a = 0; a < 3; ++a)
#pragma unroll
        for (int c2 = 0; c2 < 3; ++c2) acc[a][c2] = 0.f;
    float ssq0 = 0.f, ssq1 = 0.f;

    for (int r = 0; r < 8; ++r) {
        int y = yt * 8 + r;
        __syncthreads();

        if (t >= 192) {
            int u = t & 63;
            const float* qrow = qb + (size_t)y * Wd;
#pragma unroll
            for (int m = 0; m < 24; ++m) {
                int xo = u * 4;
                *(float4*)&qs[m][xo] = *(const float4*)(qrow + (size_t)m * HWc + xo);
            }
        } else {
            const float* m0 = midb + (size_t)(2 * p) * HWc;
            const float* m1 = m0 + HWc;
#pragma unroll
            for (int s = 0; s < 4; ++s) {
                int x0 = (t & 15) * 4 + s * 64;
                float k0[4] = {0.f, 0.f, 0.f, 0.f};
                float k1[4] = {0.f, 0.f, 0.f, 0.f};
#pragma unroll
                for (int dy = 0; dy < 3; ++dy) {
                    int yy = y + dy - 1;
                    if ((unsigned)yy < (unsigned)Hd) {
#pragma unroll
                        for (int ic = 0; ic < 2; ++ic) {
                            const float* base = (ic ? m1 : m0) + (size_t)yy * Wd;
                            float4 cv = *(const float4*)(base + x0);
                            float rr[6];
                            rr[0] = (x0 > 0) ? base[x0 - 1] : 0.f;
                            rr[1] = cv.x; rr[2] = cv.y; rr[3] = cv.z; rr[4] = cv.w;
                            rr[5] = (x0 < 252) ? base[x0 + 4] : 0.f;
                            int wb_ = ic * 9 + dy * 3;
#pragma unroll
                            for (int px = 0; px < 4; ++px) {
#pragma unroll
                                for (int dx = 0; dx < 3; ++dx) {
                                    k0[px] = fmaf(wv[wb_ + dx],      rr[px + dx], k0[px]);
                                    k1[px] = fmaf(wv[18 + wb_ + dx], rr[px + dx], k1[px]);
                                }
                            }
                        }
                    }
                }
#pragma unroll
                for (int px = 0; px < 4; ++px) {
                    ssq0 = fmaf(k0[px], k0[px], ssq0);
                    ssq1 = fmaf(k1[px], k1[px], ssq1);
                }
                *(float4*)&ks[2 * p][x0]     = *(float4*)k0;
                *(float4*)&ks[2 * p + 1][x0] = *(float4*)k1;
            }
        }
        __syncthreads();

        int n0 = wvi * 64;
#pragma unroll 4
        for (int nn = 0; nn < 16; ++nn) {
            int n = n0 + nn * 4;
            float4 q0v = *(const float4*)&qs[i0][n];
            float4 q1v = *(const float4*)&qs[i0 + 1][n];
            float4 q2v = *(const float4*)&qs[i0 + 2][n];
            float4 k0v = *(const float4*)&ks[j0][n];
            float4 k1v = *(const float4*)&ks[j0 + 1][n];
            float4 k2v = *(const float4*)&ks[j0 + 2][n];
            acc[0][0] += q0v.x*k0v.x + q0v.y*k0v.y + q0v.z*k0v.z + q0v.w*k0v.w;
            acc[0][1] += q0v.x*k1v.x + q0v.y*k1v.y + q0v.z*k1v.z + q0v.w*k1v.w;
            acc[0][2] += q0v.x*k2v.x + q0v.y*k2v.y + q0v.z*k2v.z + q0v.w*k2v.w;
            acc[1][0] += q1v.x*k0v.x + q1v.y*k0v.y + q1v.z*k0v.z + q1v.w*k0v.w;
            acc[1][1] += q1v.x*k1v.x + q1v.y*k1v.y + q1v.z*k1v.z + q1v.w*k1v.w;
            acc[1][2] += q1v.x*k2v.x + q1v.y*k2v.y + q1v.z*k2v.z + q1v.w*k2v.w;
            acc[2][0] += q2v.x*k0v.x + q2v.y*k0v.y + q2v.z*k0v.z + q2v.w*k0v.w;
            acc[2][1] += q2v.x*k1v.x + q2v.y*k1v.y + q2v.z*k1v.z + q2v.w*k1v.w;
            acc[2][2] += q2v.x*k2v.x + q2v.y*k2v.y + q2v.z*k2v.z + q2v.w*k2v.w;
        }
    }

    if (t < 192) {
        float s0 = ssq0, s1 = ssq1;
#pragma unroll
        for (int off = 8; off; off >>= 1) {
            s0 += __shfl_down(s0, off, 64);
            s1 += __shfl_down(s1, off, 64);
        }
        if ((t & 15) == 0) {
            atomicAdd(&ssq_k[b * 96 + h * 24 + 2 * p],     s0);
            atomicAdd(&ssq_k[b * 96 + h * 24 + 2 * p + 1], s1);
        }
    }

    __syncthreads();
    float* redbuf = &qs[0][0];
#pragma unroll
    for (int a = 0; a < 3; ++a)
#pragma unroll
        for (int c2 = 0; c2 < 3; ++c2)
            redbuf[wvi * 576 + (i0 + a) * 24 + (j0 + c2)] = acc[a][c2];
    __syncthreads();
    for (int p_ = t; p_ < 576; p_ += 256) {
        float s4 = redbuf[p_] + redbuf[576 + p_] + redbuf[1152 + p_] + redbuf[1728 + p_];
        atomicAdd(&attn_raw[((size_t)b * 4 + h) * 576 + p_], s4);
    }
}

// ---- softmax (+temperature, +1/(|q||k|)) then fold proj_w -> W2T[b][dv][co] ----
__global__ __launch_bounds__(256) void softmax_fold_kernel(
    const float* __restrict__ attn_raw,
    const float* __restrict__ ssq_q, const float* __restrict__ ssq_k,
    const float* __restrict__ temp, const float* __restrict__ projw,
    float* __restrict__ W2T)
{
    __shared__ float s[24][25];
    __shared__ float rq[24], rk[24];
    int h = blockIdx.x, b = blockIdx.y;
    int t = threadIdx.x;

    if (t < 24) {
        rq[t] = 1.f / fmaxf(sqrtf(ssq_q[b * 96 + h * 24 + t]), 1e-12f);
        rk[t] = 1.f / fmaxf(sqrtf(ssq_k[b * 96 + h * 24 + t]), 1e-12f);
    }
    __syncthreads();
    float T = temp[h];
    for (int p = t; p < 576; p += 256) {
        int i = p / 24, j = p % 24;
        s[i][j] = attn_raw[(size_t)(b * 4 + h) * 576 + p] * T * rq[i] * rk[j];
    }
    __syncthreads();
    if (t < 24) {
        float m = -1e30f;
#pragma unroll
        for (int j = 0; j < 24; ++j) m = fmaxf(m, s[t][j]);
        float sum = 0.f;
#pragma unroll
        for (int j = 0; j < 24; ++j) { float e = __expf(s[t][j] - m); s[t][j] = e; sum += e; }
        float inv = 1.f / sum;
#pragma unroll
        for (int j = 0; j < 24; ++j) s[t][j] *= inv;
    }
    __syncthreads();
    for (int m_ = t; m_ < 96 * 24; m_ += 256) {
        int d = m_ % 24, co = m_ / 24;
        float acc = 0.f;
#pragma unroll
        for (int c = 0; c < 24; ++c)
            acc += projw[co * 96 + h * 24 + c] * s[c][d];
        W2T[(size_t)b * 9216 + (size_t)(h * 24 + d) * 96 + co] = acc;
    }
}

// ---- fused: grouped3x3(vmid) -> v_lds (48-ch split) + GEMM out = W2 . v ----
// LDS = wls(6.9KB) + v_lds[48][132](25KB) = 32KB -> ~4-5 blocks/CU.
__global__ __launch_bounds__(256) void v_proj_kernel(
    const float* __restrict__ mid, const float* __restrict__ w2,
    const float* __restrict__ W2T, float* __restrict__ out)
{
    __shared__ float v_lds[48][132];
    __shared__ float wls[48 * 36];

    int bx = blockIdx.x, b = blockIdx.y;
    int y = bx >> 1;
    int x0 = (bx & 1) * 128;
    int t = threadIdx.x;
    const float* midb = mid + (size_t)b * 96 * HWc;

    // stage v-weights (channels 96..191 of w2): 1728 floats = 432 f4
    {
        const float* vw = w2 + 96 * 18;
        for (int i = t; i < 432; i += 256)
            *(float4*)&wls[4 * i] = *(const float4*)(vw + 4 * i);
    }

    int x = t & 127;
    int mh = __builtin_amdgcn_readfirstlane(t >> 7);
    const float* wb2 = W2T + (size_t)b * 9216 + mh * 48;
    float acc[48];
#pragma unroll
    for (int m = 0; m < 48; ++m) acc[m] = 0.f;

    int s4 = (t & 31) * 4;       // conv strip within tile, fixed per thread
    int xg = x0 + s4;

#pragma unroll 1
    for (int cc = 0; cc < 2; ++cc) {
        __syncthreads();   // wls ready / previous GEMM readers done
        // phase A: compute v channels [48*cc, 48*cc+48)
#pragma unroll
        for (int j = 0; j < 3; ++j) {
            int pair = cc * 24 + j * 8 + (t >> 5);   // per-thread constant
            const float* m0 = midb + (size_t)(2 * pair) * HWc;
            const float* m1 = m0 + HWc;
            const float* wp_ = &wls[pair * 36];      // 32-lane broadcast reads
            float k0[4] = {0.f, 0.f, 0.f, 0.f};
            float k1[4] = {0.f, 0.f, 0.f, 0.f};
#pragma unroll
            for (int dy = 0; dy < 3; ++dy) {
                int yy = y + dy - 1;
                if ((unsigned)yy < (unsigned)Hd) {   // block-uniform
#pragma unroll
                    for (int ic = 0; ic < 2; ++ic) {
                        const float* base = (ic ? m1 : m0) + (size_t)yy * Wd;
                        float4 cv = *(const float4*)(base + xg);
                        float rr[6];
                        rr[0] = (xg > 0) ? base[xg - 1] : 0.f;
                        rr[1] = cv.x; rr[2] = cv.y; rr[3] = cv.z; rr[4] = cv.w;
                        rr[5] = (xg < 252) ? base[xg + 4] : 0.f;
                        int wb_ = ic * 9 + dy * 3;
#pragma unroll
                        for (int px = 0; px < 4; ++px) {
#pragma unroll
                            for (int dx = 0; dx < 3; ++dx) {
                                k0[px] = fmaf(wp_[wb_ + dx],      rr[px + dx], k0[px]);
                                k1[px] = fmaf(wp_[18 + wb_ + dx], rr[px + dx], k1[px]);
                            }
                        }
                    }
                }
            }
            int lc = 2 * (j * 8 + (t >> 5));         // local channel in v_lds
            *(float4*)&v_lds[lc][s4]     = *(float4*)k0;
            *(float4*)&v_lds[lc + 1][s4] = *(float4*)k1;
        }
        __syncthreads();
        // phase B: GEMM accumulate channels [48*cc, 48*cc+48)
#pragma unroll 4
        for (int cl = 0; cl < 48; ++cl) {
            float v = v_lds[cl][x];
            const float* wc = wb2 + (size_t)(cc * 48 + cl) * 96;
#pragma unroll
            for (int m = 0; m < 48; ++m) acc[m] = fmaf(wc[m], v, acc[m]);
        }
    }

    float* outb = out + (size_t)b * 96 * HWc + (size_t)(mh * 48) * HWc
                + (size_t)y * Wd + x0 + x;
#pragma unroll
    for (int m = 0; m < 48; ++m) outb[(size_t)m * HWc] = acc[m];
}

extern "C" void kernel_launch(void* const* d_in, const int* in_sizes, int n_in,
                              void* d_out, int out_size, void* d_ws, size_t ws_size,
                              hipStream_t stream) {
    const float* x     = (const float*)d_in[0];
    const float* z     = (const float*)d_in[1];
    const float* kvw1  = (const float*)d_in[2];
    const float* kvw2  = (const float*)d_in[3];
    const float* qw1   = (const float*)d_in[4];
    const float* qw2   = (const float*)d_in[5];
    const float* projw = (const float*)d_in[6];
    const float* temp  = (const float*)d_in[7];
    float* out = (float*)d_out;
    float* ws  = (float*)d_ws;
    (void)in_sizes; (void)n_in; (void)out_size; (void)ws_size;

    float* ssq_q = ws + SSQ_Q_OFF;
    float* ssq_k = ws + SSQ_K_OFF;
    float* attn  = ws + ATTN_OFF;
    float* W2T   = ws + W2T_OFF;
    float* kvw1T = ws + KVW1T_OFF;
    float* qw1T  = ws + QW1T_OFF;
    float* ws1   = ws + WS1_OFF;

    hipMemsetAsync(ws, 0, (768 + 768 + 18432) * sizeof(float), stream);

    transpose_w_kernel<<<dim3(72), 256, 0, stream>>>(kvw1, kvw1T, 192, 96);
    transpose_w_kernel<<<dim3(36), 256, 0, stream>>>(qw1, qw1T, 96, 96);

    // ---- q path ----
    conv1x1_lds<<<dim3(512, 8), 256, 0, stream>>>(x, qw1T, 96, 0, ws1);              // q1
    depthwise3x3_kernel<<<dim3(8, 96, 8), 256, 0, stream>>>(ws1, qw2, out, ssq_q);   // q

    // ---- k path ----
    conv1x1_lds<<<dim3(512, 8), 256, 0, stream>>>(z, kvw1T, 192, 0, ws1);            // kmid
    k_logits_kernel<<<dim3(32, 4, 8), 256, 0, stream>>>(ws1, kvw2, out, attn, ssq_k);

    softmax_fold_kernel<<<dim3(4, 8), 256, 0, stream>>>(attn, ssq_q, ssq_k, temp, projw, W2T);

    // ---- v path ----
    conv1x1_lds<<<dim3(512, 8), 256, 0, stream>>>(z, kvw1T, 192, 96, ws1);           // vmid
    v_proj_kernel<<<dim3(512, 8), 256, 0, stream>>>(ws1, kvw2, W2T, out);
}